// Round 6
// baseline (198.275 us; speedup 1.0000x reference)
//
#include <hip/hip_runtime.h>

typedef __bf16 bf16_t;
typedef __bf16 bf16x8 __attribute__((ext_vector_type(8)));
typedef float f32x4 __attribute__((ext_vector_type(4)));
typedef float f32x16 __attribute__((ext_vector_type(16)));
typedef unsigned short u16;
typedef unsigned int u32;

#define NTOK 1025
#define NPAD 1056
#define NPADV 1088
#define BH   96
#define CDIM 768

__device__ __forceinline__ u16 f2bf(float f) {
  union { float f; unsigned u; } v; v.f = f;
  unsigned r = v.u + 0x7fffu + ((v.u >> 16) & 1u);
  return (u16)(r >> 16);
}
__device__ __forceinline__ float bf2f(u16 h) {
  union { unsigned u; float f; } v; v.u = ((unsigned)h) << 16; return v.f;
}
__device__ __forceinline__ u32 cvtpk(float lo, float hi) {
  u32 r; asm("v_cvt_pk_bf16_f32 %0, %1, %2" : "=v"(r) : "v"(lo), "v"(hi)); return r;
}
__device__ __forceinline__ void gld16(const void* g, void* l) {
  __builtin_amdgcn_global_load_lds(
      (const __attribute__((address_space(1))) unsigned*)g,
      (__attribute__((address_space(3))) unsigned*)l, 16, 0, 0);
}

// ---------------- K0a: fp32 -> bf16 convert ----------------
__global__ void conv_x(const float4* __restrict__ in, u16* __restrict__ out, int n4) {
  int i = blockIdx.x * blockDim.x + threadIdx.x;
  if (i < n4) {
    float4 f = in[i];
    ushort4 o; o.x = f2bf(f.x); o.y = f2bf(f.y); o.z = f2bf(f.z); o.w = f2bf(f.w);
    *(ushort4*)&out[i * 4] = o;
  }
}

// ---------------- K0b: transpose-convert  in[K][N] fp32 -> out[N][K] bf16 ----------------
__global__ __launch_bounds__(256) void transp(const float* __restrict__ in,
                                              u16* __restrict__ out, int K, int N) {
  __shared__ float tile[32][33];
  int n0 = blockIdx.x * 32, k0 = blockIdx.y * 32;
  int tx = threadIdx.x & 31, ty = threadIdx.x >> 5;
#pragma unroll
  for (int i = 0; i < 4; ++i)
    tile[ty + i * 8][tx] = in[(k0 + ty + i * 8) * N + n0 + tx];
  __syncthreads();
#pragma unroll
  for (int i = 0; i < 4; ++i)
    out[(n0 + ty + i * 8) * K + k0 + tx] = f2bf(tile[tx][ty + i * 8]);
}

// ---------------- K1: QKV GEMM, BK=32 3-deep ring pipeline, light epilogue ----------------
__global__ __launch_bounds__(256, 3) void qkv_gemm(
    const u16* __restrict__ A, const u16* __restrict__ Bt,
    const float* __restrict__ qbias, const float* __restrict__ vbias,
    u16* __restrict__ qkp, u16* __restrict__ vt) {
  const int M = 8200, K = 768, NB = 18;
  __shared__ u16 As[3][4096], Bs[3][4096];   // 3 x [128][32] u16, 48KB total
  // T1: bijective XCD chunking (nwg=1170 = 8*146+2 -> chunks 147,147,146x6)
  int tau0 = blockIdx.x;
  int xcd = tau0 & 7, pos = tau0 >> 3;
  int tau = (xcd < 2) ? xcd * 147 + pos : 294 + (xcd - 2) * 146 + pos;
  int bx = tau % NB, by = tau / NB;
  int m0 = by * 128, n0 = bx * 128;
  int t = threadIdx.x;
  int lane = t & 63, wave = t >> 6;
  int ln = lane & 15, hi = lane >> 4;
  int wr = wave >> 1, wc = wave & 1;
  f32x4 acc[4][4] = {};
  // staging: row = q2*64 + (t>>2), byte col = (t&3)*16, pass stride 4096B
  int srow = t >> 2;
  int off0 = t * 16;
  int ssrc = ((t & 3) * 16) ^ ((srow & 3) << 4);   // inverse-swizzled source byte col
  // read-side: byte col = (hi*16) ^ ((ln&3)<<4), row stride 64B
  int rswz = (hi * 16) ^ ((ln & 3) << 4);

  auto stage = [&](int buf, int kt) {
    int k0 = kt * 32 + (ssrc >> 1);
#pragma unroll
    for (int q2 = 0; q2 < 2; ++q2) {
      int row = q2 * 64 + srow;
      gld16(&A[(size_t)(m0 + row) * K + k0], (char*)&As[buf][0] + q2 * 4096 + off0);
      gld16(&Bt[(size_t)(n0 + row) * K + k0], (char*)&Bs[buf][0] + q2 * 4096 + off0);
    }
  };

  stage(0, 0);
  stage(1, 1);
  for (int ph = 0; ph < 24; ++ph) {
    int buf = ph % 3;
    if (ph < 22) {
      stage((ph + 2) % 3, ph + 2);
      asm volatile("s_waitcnt vmcnt(8)" ::: "memory");   // K-tile ph complete
    } else if (ph == 22) {
      asm volatile("s_waitcnt vmcnt(4)" ::: "memory");
    } else {
      asm volatile("s_waitcnt vmcnt(0)" ::: "memory");
    }
    __builtin_amdgcn_s_barrier();
    asm volatile("" ::: "memory");
    bf16x8 af[4], bfr[4];
#pragma unroll
    for (int i = 0; i < 4; ++i) {
      af[i]  = *(const bf16x8*)((const char*)&As[buf][0] + (wr * 64 + i * 16 + ln) * 64 + rswz);
      bfr[i] = *(const bf16x8*)((const char*)&Bs[buf][0] + (wc * 64 + i * 16 + ln) * 64 + rswz);
    }
    __builtin_amdgcn_s_setprio(1);
#pragma unroll
    for (int i = 0; i < 4; ++i)
#pragma unroll
      for (int j = 0; j < 4; ++j)
        acc[i][j] = __builtin_amdgcn_mfma_f32_16x16x32_bf16(af[i], bfr[j], acc[i][j], 0, 0, 0);
    __builtin_amdgcn_s_setprio(0);
    asm volatile("" ::: "memory");
    __builtin_amdgcn_s_barrier();
  }

  if (n0 < 1536) {
#pragma unroll
    for (int i = 0; i < 4; ++i) {
      int mrow = m0 + wr * 64 + i * 16 + hi * 4;
#pragma unroll
      for (int j = 0; j < 4; ++j) {
        int col = n0 + wc * 64 + j * 16 + ln;
        float bv = (col < CDIM) ? qbias[col] : 0.f;
#pragma unroll
        for (int r = 0; r < 4; ++r) {
          int m = mrow + r;
          if (m < M) qkp[(size_t)m * 1536 + col] = f2bf(acc[i][j][r] + bv);
        }
      }
    }
  } else {
#pragma unroll
    for (int i = 0; i < 4; ++i) {
      int mrow = m0 + wr * 64 + i * 16 + hi * 4;
#pragma unroll
      for (int j = 0; j < 4; ++j) {
        int col = n0 + wc * 64 + j * 16 + ln;
        int c = col - 1536;
        int h = c >> 6, d = c & 63;
        float bv = vbias[c];
#pragma unroll
        for (int r = 0; r < 4; ++r) {
          int m = mrow + r;
          if (m < M) {
            int b = m / NTOK;
            int n = m - b * NTOK;
            vt[((size_t)((b * 12 + h) * 64 + d)) * NPADV + n] = f2bf(acc[i][j][r] + bv);
          }
        }
      }
    }
  }
}

// ---------------- K2: RoPE + scatter  qkp[8200][1536] -> q,k [96][1056][64] ----------------
__global__ __launch_bounds__(256) void rope_scatter(
    const u16* __restrict__ qkp, const float* __restrict__ rope,
    u16* __restrict__ q, u16* __restrict__ k) {
  int m = blockIdx.x;
  int b = m / NTOK, n = m - b * NTOK;
  const u16* row = qkp + (size_t)m * 1536;
  const float scale = 0.125f * 1.4426950408889634f;  // 64^-0.5 * log2(e)
  int t = threadIdx.x;
#pragma unroll
  for (int it = 0; it < 3; ++it) {
    int e = t + it * 256;
    int part = (e >= 384);
    int pp = e - part * 384;
    int h = pp >> 5, d = (pp & 31) * 2;
    u32 pr = *(const u32*)&row[e * 2];
    float v0 = bf2f((u16)(pr & 0xffff)), v1 = bf2f((u16)(pr >> 16));
    float o0 = v0, o1 = v1;
    if (n > 0) {
      const float* rp = rope + (size_t)(n - 1) * 128 + d;
      float s0 = rp[0], s1 = rp[1], c0 = rp[64], c1 = rp[65];
      o0 = v0 * c0 - v1 * s0;
      o1 = v1 * c1 + v0 * s1;
    }
    if (part == 0) { o0 *= scale; o1 *= scale; }
    u32 ov = (u32)f2bf(o0) | ((u32)f2bf(o1) << 16);
    u16* dst = (part == 0 ? q : k) + ((size_t)((b * 12 + h) * NPAD + n)) * 64 + d;
    *(u32*)dst = ov;
  }
}

// ---------------- K3: flash attention, no-max exp2 softmax ----------------
__global__ __launch_bounds__(256) void flash_attn(
    const u16* __restrict__ q, const u16* __restrict__ k,
    const u16* __restrict__ vt, u16* __restrict__ y) {
  __shared__ u16 smem[2][8192];
  int f = blockIdx.x;                 // 864 = 8 XCD-chunks * 108
  int xcd = f & 7, idx = f >> 3;
  int bh = xcd * 12 + idx / 9;
  int qt = idx - (idx / 9) * 9;
  int t = threadIdx.x, lane = t & 63, w = t >> 6;
  int lq = lane & 31, h2 = lane >> 5;
  int q0 = qt * 128 + w * 32;
  bool active = (q0 < NTOK);
  int qrow = q0 + lq; if (qrow > NTOK - 1) qrow = NTOK - 1;

  const u16* qp = q + ((size_t)(bh * NPAD + qrow)) * 64;
  bf16x8 qf[4];
#pragma unroll
  for (int s = 0; s < 4; ++s)
    qf[s] = *(const bf16x8*)&qp[s * 16 + h2 * 8];

  f32x16 acc[2] = {};
  float l = 0.f;

  const size_t kbase = (size_t)bh * NPAD * 64;
  const size_t vbase = (size_t)bh * 64 * NPADV;

  auto stage = [&](int buf, int kt) {
    int t16 = t * 16;
#pragma unroll
    for (int j = 0; j < 4; ++j) {
      int off = j * 4096 + t16;
      int off2 = off & 8191;
      int row = off2 >> 7;
      int col = off2 & 127;
      int scol = col ^ ((row & 7) << 4);
      const u16* src = (j < 2)
          ? &k[kbase + (size_t)(kt + row) * 64 + (scol >> 1)]
          : &vt[vbase + (size_t)row * NPADV + kt + (scol >> 1)];
      gld16(src, (char*)&smem[buf][0] + off);
    }
  };

  stage(0, 0);
  asm volatile("s_waitcnt vmcnt(0)" ::: "memory");
  __syncthreads();

  for (int it = 0; it < 17; ++it) {
    int kt = it * 64;
    int cur = it & 1;
    if (it < 16) stage(cur ^ 1, kt + 64);

    if (active) {
      const char* kb = (const char*)&smem[cur][0];
      f32x16 sc[2] = {};
      __builtin_amdgcn_s_setprio(1);
#pragma unroll
      for (int c = 0; c < 2; ++c) {
        int krow = c * 32 + lq;
#pragma unroll
        for (int s = 0; s < 4; ++s) {
          int kcol = (s * 32 + h2 * 16) ^ ((lane & 7) << 4);
          bf16x8 kf = *(const bf16x8*)(kb + krow * 128 + kcol);
          sc[c] = __builtin_amdgcn_mfma_f32_32x32x16_bf16(kf, qf[s], sc[c], 0, 0, 0);
        }
      }
      __builtin_amdgcn_s_setprio(0);
      float p[2][16];
#pragma unroll
      for (int c = 0; c < 2; ++c)
#pragma unroll
        for (int r = 0; r < 16; ++r)
          p[c][r] = __builtin_amdgcn_exp2f(sc[c][r]);
      if (it == 16) {
#pragma unroll
        for (int c = 0; c < 2; ++c)
#pragma unroll
          for (int r = 0; r < 16; ++r) {
            int kk = kt + c * 32 + (r & 3) + 8 * (r >> 2) + 4 * h2;
            if (kk >= NTOK) p[c][r] = 0.f;
          }
      }
      float rs = 0.f;
#pragma unroll
      for (int c = 0; c < 2; ++c)
#pragma unroll
        for (int r = 0; r < 16; ++r) rs += p[c][r];
      l += rs;
      bf16x8 frag[4];
#pragma unroll
      for (int c = 0; c < 2; ++c) {
        u32 pk[8];
#pragma unroll
        for (int i = 0; i < 8; ++i) pk[i] = cvtpk(p[c][2 * i], p[c][2 * i + 1]);
        u32 x0 = __shfl_xor(pk[0], 32, 64), x1 = __shfl_xor(pk[1], 32, 64);
        u32 x2 = __shfl_xor(pk[2], 32, 64), x3 = __shfl_xor(pk[3], 32, 64);
        u32 x4 = __shfl_xor(pk[4], 32, 64), x5 = __shfl_xor(pk[5], 32, 64);
        u32 x6 = __shfl_xor(pk[6], 32, 64), x7 = __shfl_xor(pk[7], 32, 64);
        union { u32 u[4]; bf16x8 v; } u0, u1;
        u0.u[0] = h2 ? x2 : pk[0];  u0.u[1] = h2 ? x3 : pk[1];
        u0.u[2] = h2 ? pk[2] : x0;  u0.u[3] = h2 ? pk[3] : x1;
        u1.u[0] = h2 ? x6 : pk[4];  u1.u[1] = h2 ? x7 : pk[5];
        u1.u[2] = h2 ? pk[6] : x4;  u1.u[3] = h2 ? pk[7] : x5;
        frag[c * 2] = u0.v; frag[c * 2 + 1] = u1.v;
      }
      __builtin_amdgcn_s_setprio(1);
#pragma unroll
      for (int hf = 0; hf < 2; ++hf) {
        int vrow = hf * 32 + lq;
#pragma unroll
        for (int s = 0; s < 4; ++s) {
          int vcol = (s * 32 + h2 * 16) ^ ((lane & 7) << 4);
          bf16x8 vf = *(const bf16x8*)(kb + 8192 + vrow * 128 + vcol);
          acc[hf] = __builtin_amdgcn_mfma_f32_32x32x16_bf16(vf, frag[s], acc[hf], 0, 0, 0);
        }
      }
      __builtin_amdgcn_s_setprio(0);
    }
    asm volatile("s_waitcnt vmcnt(0)" ::: "memory");
    __syncthreads();
  }

  int row = q0 + lq;
  if (active && row < NTOK) {
    float lt = l + __shfl_xor(l, 32, 64);
    float inv = 1.f / lt;
    int b = bh / 12, h = bh - b * 12;
    u16* yr = y + ((size_t)(b * NTOK + row)) * CDIM + h * 64;
#pragma unroll
    for (int hf = 0; hf < 2; ++hf)
#pragma unroll
      for (int g = 0; g < 4; ++g) {
        int d0 = hf * 32 + 8 * g + 4 * h2;
        ushort4 o;
        o.x = f2bf(acc[hf][g * 4 + 0] * inv);
        o.y = f2bf(acc[hf][g * 4 + 1] * inv);
        o.z = f2bf(acc[hf][g * 4 + 2] * inv);
        o.w = f2bf(acc[hf][g * 4 + 3] * inv);
        *(ushort4*)&yr[d0] = o;
      }
  }
}

// ---------------- K4: LayerNorm (bf16 in) -> bf16 ----------------
__global__ __launch_bounds__(256) void lnorm(const u16* __restrict__ y,
                                             const float* __restrict__ gamma,
                                             const float* __restrict__ beta,
                                             u16* __restrict__ out) {
  int row = blockIdx.x;
  const u16* yr = y + (size_t)row * CDIM;
  int t = threadIdx.x;
  float v[3];
  float s = 0.f, s2 = 0.f;
#pragma unroll
  for (int i = 0; i < 3; ++i) {
    v[i] = bf2f(yr[t + 256 * i]);
    s += v[i]; s2 += v[i] * v[i];
  }
#pragma unroll
  for (int msk = 1; msk < 64; msk <<= 1) {
    s  += __shfl_xor(s, msk, 64);
    s2 += __shfl_xor(s2, msk, 64);
  }
  __shared__ float ws[8];
  int w = t >> 6, lane = t & 63;
  if (lane == 0) { ws[w] = s; ws[4 + w] = s2; }
  __syncthreads();
  s = ws[0] + ws[1] + ws[2] + ws[3];
  s2 = ws[4] + ws[5] + ws[6] + ws[7];
  float mu = s * (1.f / 768.f);
  float var = s2 * (1.f / 768.f) - mu * mu;
  float rstd = rsqrtf(var + 1e-6f);
#pragma unroll
  for (int i = 0; i < 3; ++i) {
    int c = t + 256 * i;
    out[(size_t)row * CDIM + c] = f2bf((v[i] - mu) * rstd * gamma[c] + beta[c]);
  }
}

// ---------------- K5: proj GEMM, BK=32 3-deep ring pipeline -> fp32 ----------------
__global__ __launch_bounds__(256, 3) void proj_gemm(
    const u16* __restrict__ A, const u16* __restrict__ Bt,
    const float* __restrict__ bias, float* __restrict__ out) {
  const int M = 8200, K = 768, NB = 6;
  __shared__ u16 As[3][4096], Bs[3][4096];
  // nwg=390 = 8*48+6 -> chunks 49x6, 48x2
  int tau0 = blockIdx.x;
  int xcd = tau0 & 7, pos = tau0 >> 3;
  int tau = (xcd < 6) ? xcd * 49 + pos : 294 + (xcd - 6) * 48 + pos;
  int bx = tau % NB, by = tau / NB;
  int m0 = by * 128, n0 = bx * 128;
  int t = threadIdx.x;
  int lane = t & 63, wave = t >> 6;
  int ln = lane & 15, hi = lane >> 4;
  int wr = wave >> 1, wc = wave & 1;
  f32x4 acc[4][4] = {};
  int srow = t >> 2;
  int off0 = t * 16;
  int ssrc = ((t & 3) * 16) ^ ((srow & 3) << 4);
  int rswz = (hi * 16) ^ ((ln & 3) << 4);

  auto stage = [&](int buf, int kt) {
    int k0 = kt * 32 + (ssrc >> 1);
#pragma unroll
    for (int q2 = 0; q2 < 2; ++q2) {
      int row = q2 * 64 + srow;
      gld16(&A[(size_t)(m0 + row) * K + k0], (char*)&As[buf][0] + q2 * 4096 + off0);
      gld16(&Bt[(size_t)(n0 + row) * K + k0], (char*)&Bs[buf][0] + q2 * 4096 + off0);
    }
  };

  stage(0, 0);
  stage(1, 1);
  for (int ph = 0; ph < 24; ++ph) {
    int buf = ph % 3;
    if (ph < 22) {
      stage((ph + 2) % 3, ph + 2);
      asm volatile("s_waitcnt vmcnt(8)" ::: "memory");
    } else if (ph == 22) {
      asm volatile("s_waitcnt vmcnt(4)" ::: "memory");
    } else {
      asm volatile("s_waitcnt vmcnt(0)" ::: "memory");
    }
    __builtin_amdgcn_s_barrier();
    asm volatile("" ::: "memory");
    bf16x8 af[4], bfr[4];
#pragma unroll
    for (int i = 0; i < 4; ++i) {
      af[i]  = *(const bf16x8*)((const char*)&As[buf][0] + (wr * 64 + i * 16 + ln) * 64 + rswz);
      bfr[i] = *(const bf16x8*)((const char*)&Bs[buf][0] + (wc * 64 + i * 16 + ln) * 64 + rswz);
    }
    __builtin_amdgcn_s_setprio(1);
#pragma unroll
    for (int i = 0; i < 4; ++i)
#pragma unroll
      for (int j = 0; j < 4; ++j)
        acc[i][j] = __builtin_amdgcn_mfma_f32_16x16x32_bf16(af[i], bfr[j], acc[i][j], 0, 0, 0);
    __builtin_amdgcn_s_setprio(0);
    asm volatile("" ::: "memory");
    __builtin_amdgcn_s_barrier();
  }
#pragma unroll
  for (int i = 0; i < 4; ++i) {
    int mrow = m0 + wr * 64 + i * 16 + hi * 4;
#pragma unroll
    for (int j = 0; j < 4; ++j) {
      int col = n0 + wc * 64 + j * 16 + ln;
      float bv = bias[col];
#pragma unroll
      for (int r = 0; r < 4; ++r) {
        int m = mrow + r;
        if (m < M) out[(size_t)m * CDIM + col] = acc[i][j][r] + bv;
      }
    }
  }
}

extern "C" void kernel_launch(void* const* d_in, const int* in_sizes, int n_in,
                              void* d_out, int out_size, void* d_ws, size_t ws_size,
                              hipStream_t stream) {
  const float* x      = (const float*)d_in[0];
  const float* rope   = (const float*)d_in[1];
  const float* w_qkv  = (const float*)d_in[2];
  const float* q_bias = (const float*)d_in[3];
  const float* v_bias = (const float*)d_in[4];
  const float* gamma  = (const float*)d_in[5];
  const float* beta   = (const float*)d_in[6];
  const float* w_proj = (const float*)d_in[7];
  const float* b_proj = (const float*)d_in[8];
  float* out = (float*)d_out;

  // Aliased workspace regions (total 65.7 MB):
  //  A [0, 12.98M):    xb -> qbuf -> ylb
  //  B [12.98M, 25.95M): wqkvt -> kbuf
  //  C [25.95M, 51.14M): qkp[8200][1536] -> ybf
  //  D [51.14M, 64.51M): vtbuf
  //  E [64.51M, 65.69M): wprjt
  char* ws = (char*)d_ws;
  u16* xb    = (u16*)(ws);                    // A
  u16* qbuf  = (u16*)(ws);                    // A
  u16* ylb   = (u16*)(ws);                    // A
  u16* wqkvt = (u16*)(ws + 12976128);         // B
  u16* kbuf  = (u16*)(ws + 12976128);         // B
  u16* qkp   = (u16*)(ws + 25952256);         // C
  u16* ybf   = (u16*)(ws + 25952256);         // C
  u16* vtbuf = (u16*)(ws + 51142656);         // D
  u16* wprjt = (u16*)(ws + 64512000);         // E

  hipMemsetAsync(vtbuf, 0, 13369344, stream);

  conv_x<<<(1574400 + 255) / 256, 256, 0, stream>>>((const float4*)x, xb, 1574400);
  transp<<<dim3(2304 / 32, 768 / 32), 256, 0, stream>>>(w_qkv, wqkvt, 768, 2304);
  transp<<<dim3(768 / 32, 768 / 32), 256, 0, stream>>>(w_proj, wprjt, 768, 768);

  qkv_gemm<<<dim3(1170), 256, 0, stream>>>(xb, wqkvt, q_bias, v_bias, qkp, vtbuf);
  rope_scatter<<<dim3(8200), 256, 0, stream>>>(qkp, rope, qbuf, kbuf);
  flash_attn<<<dim3(864), 256, 0, stream>>>(qbuf, kbuf, vtbuf, ybf);
  lnorm<<<8200, 256, 0, stream>>>(ybf, gamma, beta, ylb);
  proj_gemm<<<dim3(390), 256, 0, stream>>>(ylb, wprjt, b_proj, out);
}

// Round 7
// 169.490 us; speedup vs baseline: 1.1698x; 1.1698x over previous
//
#include <hip/hip_runtime.h>

typedef __bf16 bf16_t;
typedef __bf16 bf16x8 __attribute__((ext_vector_type(8)));
typedef float f32x4 __attribute__((ext_vector_type(4)));
typedef float f32x16 __attribute__((ext_vector_type(16)));
typedef unsigned short u16;
typedef unsigned int u32;

#define NTOK 1025
#define MTOT 8200
#define MPAD 8448
#define CDIM 768

__device__ __forceinline__ u16 f2bf(float f) {
  union { float f; unsigned u; } v; v.f = f;
  unsigned r = v.u + 0x7fffu + ((v.u >> 16) & 1u);
  return (u16)(r >> 16);
}
__device__ __forceinline__ float bf2f(u16 h) {
  union { unsigned u; float f; } v; v.u = ((unsigned)h) << 16; return v.f;
}
__device__ __forceinline__ u32 cvtpk(float lo, float hi) {
  u32 r; asm("v_cvt_pk_bf16_f32 %0, %1, %2" : "=v"(r) : "v"(lo), "v"(hi)); return r;
}
__device__ __forceinline__ void gld16(const void* g, void* l) {
  __builtin_amdgcn_global_load_lds(
      (const __attribute__((address_space(1))) unsigned*)g,
      (__attribute__((address_space(3))) unsigned*)l, 16, 0, 0);
}

// ---------------- K0a: fp32 -> bf16 convert ----------------
__global__ void conv_x(const float4* __restrict__ in, u16* __restrict__ out, int n4) {
  int i = blockIdx.x * blockDim.x + threadIdx.x;
  if (i < n4) {
    float4 f = in[i];
    ushort4 o; o.x = f2bf(f.x); o.y = f2bf(f.y); o.z = f2bf(f.z); o.w = f2bf(f.w);
    *(ushort4*)&out[i * 4] = o;
  }
}

// ---------------- K0b: transpose-convert  in[K][N] fp32 -> out[N][K] bf16 ----------------
__global__ __launch_bounds__(256) void transp(const float* __restrict__ in,
                                              u16* __restrict__ out, int K, int N) {
  __shared__ float tile[32][33];
  int n0 = blockIdx.x * 32, k0 = blockIdx.y * 32;
  int tx = threadIdx.x & 31, ty = threadIdx.x >> 5;
#pragma unroll
  for (int i = 0; i < 4; ++i)
    tile[ty + i * 8][tx] = in[(k0 + ty + i * 8) * N + n0 + tx];
  __syncthreads();
#pragma unroll
  for (int i = 0; i < 4; ++i)
    out[(n0 + ty + i * 8) * K + k0 + tx] = f2bf(tile[tx][ty + i * 8]);
}

// ---------------- shared 128x128 K-loop (single-buffer, swizzled, r4-proven) ----------------
// TRANS=false: acc[x][y]: x = token-frag (A), y = feature-frag (Bt)
// TRANS=true : acc[x][y]: x = feature-frag (Bt), y = token-frag (A)   (C^T fragments)
template <bool TRANS>
__device__ __forceinline__ void kloop128(const u16* __restrict__ A, const u16* __restrict__ Bt,
                                         int m0, int n0, u16* As, u16* Bs, int t,
                                         f32x4 (*acc)[4]) {
  const int K = 768;
  int lane = t & 63, wave = t >> 6;
  int ln = lane & 15, hi = lane >> 4;
  int wr = wave >> 1, wc = wave & 1;
  int swz = (ln & 7) << 4;
  int trow = t >> 3;
  int tcolb = (t & 7) * 16;
  int scol = ((tcolb ^ ((trow & 7) << 4)) >> 1);

  for (int k0 = 0; k0 < K; k0 += 64) {
#pragma unroll
    for (int c = 0; c < 4; ++c) {
      gld16(&A[(size_t)(m0 + c * 32 + trow) * K + k0 + scol], &As[c * 2048 + t * 8]);
      gld16(&Bt[(size_t)(n0 + c * 32 + trow) * K + k0 + scol], &Bs[c * 2048 + t * 8]);
    }
    asm volatile("s_waitcnt vmcnt(0)" ::: "memory");
    __builtin_amdgcn_s_barrier();
    asm volatile("" ::: "memory");
#pragma unroll
    for (int kk = 0; kk < 2; ++kk) {
      bf16x8 af[4], bfr[4];
#pragma unroll
      for (int i = 0; i < 4; ++i)
        af[i] = *(const bf16x8*)((const char*)&As[(wr * 64 + i * 16 + ln) * 64]
                                 + ((kk * 64 + hi * 16) ^ swz));
#pragma unroll
      for (int j = 0; j < 4; ++j)
        bfr[j] = *(const bf16x8*)((const char*)&Bs[(wc * 64 + j * 16 + ln) * 64]
                                  + ((kk * 64 + hi * 16) ^ swz));
      __builtin_amdgcn_s_setprio(1);
#pragma unroll
      for (int x = 0; x < 4; ++x)
#pragma unroll
        for (int y = 0; y < 4; ++y)
          acc[x][y] = TRANS
              ? __builtin_amdgcn_mfma_f32_16x16x32_bf16(bfr[x], af[y], acc[x][y], 0, 0, 0)
              : __builtin_amdgcn_mfma_f32_16x16x32_bf16(af[x], bfr[y], acc[x][y], 0, 0, 0);
      __builtin_amdgcn_s_setprio(0);
    }
    asm volatile("" ::: "memory");
    __builtin_amdgcn_s_barrier();
  }
}

// ---------------- K1a: QKV GEMM for q/k cols (transposed frags) + bias + RoPE fused ----------------
// q,k out: [12][MPAD][64] bf16 (global-m rows)
__global__ __launch_bounds__(256) void qkv_gemm_t(
    const u16* __restrict__ A, const u16* __restrict__ Bt,
    const float* __restrict__ qbias, const float* __restrict__ rope,
    u16* __restrict__ q, u16* __restrict__ k) {
  const int NB = 12;
  __shared__ u16 As[8192], Bs[8192];
  // bijective XCD chunking: nwg=780 = 8*97+4 -> xcd<4: 98, else 97
  int tau0 = blockIdx.x;
  int xcd = tau0 & 7, pos = tau0 >> 3;
  int tau = (xcd < 4) ? xcd * 98 + pos : 392 + (xcd - 4) * 97 + pos;
  int bx = tau % NB, by = tau / NB;
  int m0 = by * 128, n0 = bx * 128;
  int t = threadIdx.x;
  int lane = t & 63, wave = t >> 6;
  int ln = lane & 15, hi = lane >> 4;
  int wr = wave >> 1, wc = wave & 1;

  f32x4 acc[4][4] = {};
  kloop128<true>(A, Bt, m0, n0, As, Bs, t, acc);

  const float scale = 0.125f * 1.4426950408889634f;  // 64^-0.5 * log2(e)
#pragma unroll
  for (int ii = 0; ii < 4; ++ii) {
    int m = m0 + wr * 64 + ii * 16 + ln;         // token (per-lane)
    if (m < MTOT) {
      int b = m / NTOK;
      int n = m - b * NTOK;
      const float* rp = rope + (size_t)(n - 1) * 128;
#pragma unroll
      for (int jj = 0; jj < 4; ++jj) {
        int c4 = n0 + wc * 64 + jj * 16 + hi * 4;   // 4 consecutive features
        int part = (c4 >= CDIM) ? 1 : 0;
        int cc = c4 - part * CDIM;
        int h = cc >> 6, d4 = cc & 63;
        float v0 = acc[jj][ii][0], v1 = acc[jj][ii][1];
        float v2 = acc[jj][ii][2], v3 = acc[jj][ii][3];
        if (part == 0) {
          float4 qb = *(const float4*)(qbias + cc);
          v0 += qb.x; v1 += qb.y; v2 += qb.z; v3 += qb.w;
        }
        float o0, o1, o2, o3;
        if (n > 0) {
          float4 sn = *(const float4*)(rp + d4);
          float4 cs = *(const float4*)(rp + 64 + d4);
          o0 = v0 * cs.x - v1 * sn.x;
          o1 = v1 * cs.y + v0 * sn.y;
          o2 = v2 * cs.z - v3 * sn.z;
          o3 = v3 * cs.w + v2 * sn.w;
        } else { o0 = v0; o1 = v1; o2 = v2; o3 = v3; }
        if (part == 0) { o0 *= scale; o1 *= scale; o2 *= scale; o3 *= scale; }
        uint2 w; w.x = cvtpk(o0, o1); w.y = cvtpk(o2, o3);
        u16* dst = (part ? k : q) + ((size_t)(h * MPAD + m)) * 64 + d4;
        *(uint2*)dst = w;                         // 8B aligned (d4 % 4 == 0)
      }
    }
  }
}

// ---------------- K1b: QKV GEMM for v cols (normal frags) + bias -> vt [12][64][MPAD] ----------------
__global__ __launch_bounds__(256) void qkv_gemm_v(
    const u16* __restrict__ A, const u16* __restrict__ Bt,
    const float* __restrict__ vbias, u16* __restrict__ vt) {
  const int NB = 6;
  __shared__ u16 As[8192], Bs[8192];
  // nwg=390 = 8*48+6 -> xcd<6: 49, else 48
  int tau0 = blockIdx.x;
  int xcd = tau0 & 7, pos = tau0 >> 3;
  int tau = (xcd < 6) ? xcd * 49 + pos : 294 + (xcd - 6) * 48 + pos;
  int bx = tau % NB, by = tau / NB;
  int m0 = by * 128, n0 = 1536 + bx * 128;
  int t = threadIdx.x;
  int lane = t & 63, wave = t >> 6;
  int ln = lane & 15, hi = lane >> 4;
  int wr = wave >> 1, wc = wave & 1;

  f32x4 acc[4][4] = {};
  kloop128<false>(A, Bt, m0, n0, As, Bs, t, acc);

#pragma unroll
  for (int i = 0; i < 4; ++i) {
    int mrow = m0 + wr * 64 + i * 16 + hi * 4;     // 4 consecutive tokens
    if (mrow < MTOT) {
      bool full = (mrow + 3 < MTOT);
#pragma unroll
      for (int j = 0; j < 4; ++j) {
        int cv = n0 - 1536 + wc * 64 + j * 16 + ln;
        int h = cv >> 6, d = cv & 63;
        float vb = vbias[cv];
        float v0 = acc[i][j][0] + vb, v1 = acc[i][j][1] + vb;
        float v2 = acc[i][j][2] + vb, v3 = acc[i][j][3] + vb;
        u16* dst = vt + ((size_t)(h * 64 + d)) * MPAD + mrow;
        if (full) {
          uint2 w; w.x = cvtpk(v0, v1); w.y = cvtpk(v2, v3);
          *(uint2*)dst = w;                       // mrow % 4 == 0 -> 8B aligned
        } else {
          float vv[4] = {v0, v1, v2, v3};
#pragma unroll
          for (int r = 0; r < 4; ++r)
            if (mrow + r < MTOT) dst[r] = f2bf(vv[r]);
        }
      }
    }
  }
}

// ---------------- K3: flash attention, no-max exp2 softmax ----------------
// q,k: [12][MPAD][64] ; vt: [12][64][MPAD] ; y: [8200][768] bf16
__global__ __launch_bounds__(256) void flash_attn(
    const u16* __restrict__ q, const u16* __restrict__ k,
    const u16* __restrict__ vt, u16* __restrict__ y) {
  __shared__ u16 smem[2][8192];
  int f = blockIdx.x;                 // 864 = 8 XCD-chunks * 108
  int xcd = f & 7, idx = f >> 3;
  int bh = xcd * 12 + idx / 9;
  int qt = idx - (idx / 9) * 9;
  int b = bh / 12, h = bh - b * 12;
  int t = threadIdx.x, lane = t & 63, w = t >> 6;
  int lq = lane & 31, h2 = lane >> 5;
  int q0 = qt * 128 + w * 32;
  bool active = (q0 < NTOK);
  int qrow = q0 + lq; if (qrow > NTOK - 1) qrow = NTOK - 1;

  const size_t kbase = ((size_t)h * MPAD + (size_t)b * NTOK) * 64;
  const size_t vbase = (size_t)h * 64 * MPAD + (size_t)b * NTOK;

  const u16* qp = q + kbase + (size_t)qrow * 64;
  bf16x8 qf[4];
#pragma unroll
  for (int s = 0; s < 4; ++s)
    qf[s] = *(const bf16x8*)&qp[s * 16 + h2 * 8];

  f32x16 acc[2] = {};
  float l = 0.f;

  auto stage = [&](int buf, int kt) {
    int t16 = t * 16;
#pragma unroll
    for (int j = 0; j < 4; ++j) {
      int off = j * 4096 + t16;
      int off2 = off & 8191;
      int row = off2 >> 7;
      int col = off2 & 127;
      int scol = col ^ ((row & 7) << 4);
      const u16* src = (j < 2)
          ? &k[kbase + (size_t)(kt + row) * 64 + (scol >> 1)]
          : &vt[vbase + (size_t)row * MPAD + kt + (scol >> 1)];
      gld16(src, (char*)&smem[buf][0] + off);
    }
  };

  stage(0, 0);
  asm volatile("s_waitcnt vmcnt(0)" ::: "memory");
  __syncthreads();

  for (int it = 0; it < 17; ++it) {
    int kt = it * 64;
    int cur = it & 1;
    if (it < 16) stage(cur ^ 1, kt + 64);

    if (active) {
      const char* kb = (const char*)&smem[cur][0];
      f32x16 sc[2] = {};
      __builtin_amdgcn_s_setprio(1);
#pragma unroll
      for (int c = 0; c < 2; ++c) {
        int krow = c * 32 + lq;
#pragma unroll
        for (int s = 0; s < 4; ++s) {
          int kcol = (s * 32 + h2 * 16) ^ ((lane & 7) << 4);
          bf16x8 kf = *(const bf16x8*)(kb + krow * 128 + kcol);
          sc[c] = __builtin_amdgcn_mfma_f32_32x32x16_bf16(kf, qf[s], sc[c], 0, 0, 0);
        }
      }
      __builtin_amdgcn_s_setprio(0);
      float p[2][16];
#pragma unroll
      for (int c = 0; c < 2; ++c)
#pragma unroll
        for (int r = 0; r < 16; ++r)
          p[c][r] = __builtin_amdgcn_exp2f(sc[c][r]);
      if (it == 16) {
#pragma unroll
        for (int c = 0; c < 2; ++c)
#pragma unroll
          for (int r = 0; r < 16; ++r) {
            int kk = kt + c * 32 + (r & 3) + 8 * (r >> 2) + 4 * h2;
            if (kk >= NTOK) p[c][r] = 0.f;
          }
      }
      float rs = 0.f;
#pragma unroll
      for (int c = 0; c < 2; ++c)
#pragma unroll
        for (int r = 0; r < 16; ++r) rs += p[c][r];
      l += rs;
      bf16x8 frag[4];
#pragma unroll
      for (int c = 0; c < 2; ++c) {
        u32 pk[8];
#pragma unroll
        for (int i = 0; i < 8; ++i) pk[i] = cvtpk(p[c][2 * i], p[c][2 * i + 1]);
        u32 x0 = __shfl_xor(pk[0], 32, 64), x1 = __shfl_xor(pk[1], 32, 64);
        u32 x2 = __shfl_xor(pk[2], 32, 64), x3 = __shfl_xor(pk[3], 32, 64);
        u32 x4 = __shfl_xor(pk[4], 32, 64), x5 = __shfl_xor(pk[5], 32, 64);
        u32 x6 = __shfl_xor(pk[6], 32, 64), x7 = __shfl_xor(pk[7], 32, 64);
        union { u32 u[4]; bf16x8 v; } u0, u1;
        u0.u[0] = h2 ? x2 : pk[0];  u0.u[1] = h2 ? x3 : pk[1];
        u0.u[2] = h2 ? pk[2] : x0;  u0.u[3] = h2 ? pk[3] : x1;
        u1.u[0] = h2 ? x6 : pk[4];  u1.u[1] = h2 ? x7 : pk[5];
        u1.u[2] = h2 ? pk[6] : x4;  u1.u[3] = h2 ? pk[7] : x5;
        frag[c * 2] = u0.v; frag[c * 2 + 1] = u1.v;
      }
      __builtin_amdgcn_s_setprio(1);
#pragma unroll
      for (int hf = 0; hf < 2; ++hf) {
        int vrow = hf * 32 + lq;
#pragma unroll
        for (int s = 0; s < 4; ++s) {
          int vcol = (s * 32 + h2 * 16) ^ ((lane & 7) << 4);
          bf16x8 vf = *(const bf16x8*)(kb + 8192 + vrow * 128 + vcol);
          acc[hf] = __builtin_amdgcn_mfma_f32_32x32x16_bf16(vf, frag[s], acc[hf], 0, 0, 0);
        }
      }
      __builtin_amdgcn_s_setprio(0);
    }
    asm volatile("s_waitcnt vmcnt(0)" ::: "memory");
    __syncthreads();
  }

  int row = q0 + lq;
  if (active && row < NTOK) {
    float lt = l + __shfl_xor(l, 32, 64);
    float inv = 1.f / lt;
    u16* yr = y + ((size_t)(b * NTOK + row)) * CDIM + h * 64;
#pragma unroll
    for (int hf = 0; hf < 2; ++hf)
#pragma unroll
      for (int g = 0; g < 4; ++g) {
        int d0 = hf * 32 + 8 * g + 4 * h2;
        ushort4 o;
        o.x = f2bf(acc[hf][g * 4 + 0] * inv);
        o.y = f2bf(acc[hf][g * 4 + 1] * inv);
        o.z = f2bf(acc[hf][g * 4 + 2] * inv);
        o.w = f2bf(acc[hf][g * 4 + 3] * inv);
        *(ushort4*)&yr[d0] = o;
      }
  }
}

// ---------------- K4: LayerNorm (bf16 in) -> bf16 ----------------
__global__ __launch_bounds__(256) void lnorm(const u16* __restrict__ y,
                                             const float* __restrict__ gamma,
                                             const float* __restrict__ beta,
                                             u16* __restrict__ out) {
  int row = blockIdx.x;
  const u16* yr = y + (size_t)row * CDIM;
  int t = threadIdx.x;
  float v[3];
  float s = 0.f, s2 = 0.f;
#pragma unroll
  for (int i = 0; i < 3; ++i) {
    v[i] = bf2f(yr[t + 256 * i]);
    s += v[i]; s2 += v[i] * v[i];
  }
#pragma unroll
  for (int msk = 1; msk < 64; msk <<= 1) {
    s  += __shfl_xor(s, msk, 64);
    s2 += __shfl_xor(s2, msk, 64);
  }
  __shared__ float ws[8];
  int w = t >> 6, lane = t & 63;
  if (lane == 0) { ws[w] = s; ws[4 + w] = s2; }
  __syncthreads();
  s = ws[0] + ws[1] + ws[2] + ws[3];
  s2 = ws[4] + ws[5] + ws[6] + ws[7];
  float mu = s * (1.f / 768.f);
  float var = s2 * (1.f / 768.f) - mu * mu;
  float rstd = rsqrtf(var + 1e-6f);
#pragma unroll
  for (int i = 0; i < 3; ++i) {
    int c = t + 256 * i;
    out[(size_t)row * CDIM + c] = f2bf((v[i] - mu) * rstd * gamma[c] + beta[c]);
  }
}

// ---------------- K5: proj GEMM (transposed frags) + bias -> fp32, float4 stores ----------------
__global__ __launch_bounds__(256) void proj_gemm(
    const u16* __restrict__ A, const u16* __restrict__ Bt,
    const float* __restrict__ bias, float* __restrict__ out) {
  const int NB = 6;
  __shared__ u16 As[8192], Bs[8192];
  int tau0 = blockIdx.x;
  int xcd = tau0 & 7, pos = tau0 >> 3;
  int tau = (xcd < 6) ? xcd * 49 + pos : 294 + (xcd - 6) * 48 + pos;
  int bx = tau % NB, by = tau / NB;
  int m0 = by * 128, n0 = bx * 128;
  int t = threadIdx.x;
  int lane = t & 63, wave = t >> 6;
  int ln = lane & 15, hi = lane >> 4;
  int wr = wave >> 1, wc = wave & 1;

  f32x4 acc[4][4] = {};
  kloop128<true>(A, Bt, m0, n0, As, Bs, t, acc);

#pragma unroll
  for (int ii = 0; ii < 4; ++ii) {
    int m = m0 + wr * 64 + ii * 16 + ln;
    if (m < MTOT) {
      float* dr = out + (size_t)m * CDIM;
#pragma unroll
      for (int jj = 0; jj < 4; ++jj) {
        int c4 = n0 + wc * 64 + jj * 16 + hi * 4;
        float4 bv = *(const float4*)(bias + c4);
        float4 o;
        o.x = acc[jj][ii][0] + bv.x;
        o.y = acc[jj][ii][1] + bv.y;
        o.z = acc[jj][ii][2] + bv.z;
        o.w = acc[jj][ii][3] + bv.w;
        *(float4*)(dr + c4) = o;                  // 16B aligned
      }
    }
  }
}

extern "C" void kernel_launch(void* const* d_in, const int* in_sizes, int n_in,
                              void* d_out, int out_size, void* d_ws, size_t ws_size,
                              hipStream_t stream) {
  const float* x      = (const float*)d_in[0];
  const float* rope   = (const float*)d_in[1];
  const float* w_qkv  = (const float*)d_in[2];
  const float* q_bias = (const float*)d_in[3];
  const float* v_bias = (const float*)d_in[4];
  const float* gamma  = (const float*)d_in[5];
  const float* beta   = (const float*)d_in[6];
  const float* w_proj = (const float*)d_in[7];
  const float* b_proj = (const float*)d_in[8];
  float* out = (float*)d_out;

  // Workspace (56.6 MB, no qkp, no memset):
  //  A [0, 12.98M):        xb -> ybf
  //  [12.98M, 16.52M):     wqkvt
  //  [16.52M, 17.69M):     wprjt
  //  B [17.69M, 30.67M):   qbuf [12][8448][64] -> ylb
  //  [30.67M, 43.65M):     kbuf [12][8448][64]
  //  [43.65M, 56.62M):     vtg  [12][64][8448]
  char* ws = (char*)d_ws;
  u16* xb    = (u16*)(ws);
  u16* ybf   = (u16*)(ws);
  u16* wqkvt = (u16*)(ws + 12976128);
  u16* wprjt = (u16*)(ws + 16515072);
  u16* qbuf  = (u16*)(ws + 17694720);
  u16* ylb   = (u16*)(ws + 17694720);
  u16* kbuf  = (u16*)(ws + 30670848);
  u16* vtg   = (u16*)(ws + 43646976);

  conv_x<<<(1574400 + 255) / 256, 256, 0, stream>>>((const float4*)x, xb, 1574400);
  transp<<<dim3(2304 / 32, 768 / 32), 256, 0, stream>>>(w_qkv, wqkvt, 768, 2304);
  transp<<<dim3(768 / 32, 768 / 32), 256, 0, stream>>>(w_proj, wprjt, 768, 768);

  qkv_gemm_t<<<dim3(780), 256, 0, stream>>>(xb, wqkvt, q_bias, rope, qbuf, kbuf);
  qkv_gemm_v<<<dim3(390), 256, 0, stream>>>(xb, wqkvt, v_bias, vtg);
  flash_attn<<<dim3(864), 256, 0, stream>>>(qbuf, kbuf, vtg, ybf);
  lnorm<<<8200, 256, 0, stream>>>(ybf, gamma, beta, ylb);
  proj_gemm<<<dim3(390), 256, 0, stream>>>(ylb, wprjt, b_proj, out);
}